// Round 4
// baseline (309.977 us; speedup 1.0000x reference)
//
#include <hip/hip_runtime.h>

// SimVQ: x[8,2048,512] f32, codebook[8192,512] f32, W[512,512] f32
// out = concat(quantized[16384*512], indices[16384] (as f32), commit_loss[1])
//
// Round 10:
//  R9 post-mortem: d2 pipeline changes exhausted (145us; VALU-pipe-bound at 54%,
//  emission butterfly is the floor). The OTHER 147us was never profiled (top-5 all
//  d2). This round: d2 untouched; attack the hidden half:
//  - codes_mfma: 512 thr / 8 waves (wave tile 32x64, acc[2][4]) on the same
//    128x128 tile. It ran 1 block/CU with 4 waves (12.5% occ) -> latency-starved.
//  - refine_gather: quad-parallel candidate dots (4 in flight, one per 16-lane
//    quad, 32 elems/lane, 4-level quad reduce) vs serial 64-lane evaluations.
//    Exact (d2, idx) lexicographic final reduce keeps argmin tie semantics.

#define DIMK  512
#define CBN   8192
#define MROWS 16384

#define SX 24.0f
#define SC 500.0f
#define INV_SS (1.0f / (SX * SC))
#define DKEY  1231
#define NSLOT 3

// ws layout (bytes)
#define WS_CODES   0UL          // 8192*512*4    = 16,777,216
#define WS_XQ      16777216UL   // 16384*512     =  8,388,608
#define WS_CQ      25165824UL   // 8192*512      =  4,194,304
#define WS_NORMS   29360128UL   // 8192*4
#define WS_CAND    29392896UL   // 16384*128*3*4 = 25,165,824
#define WS_CBH     29392896UL   // alias: cb hi (consumed before d2 writes cand)
#define WS_CBL     37781504UL   // alias: cb lo
#define WS_WH      54558720UL   // 512*512*2 = 524,288
#define WS_WL      55083008UL
#define WS_LOSSP   55607296UL   // 16384*4
// end ~55.7 MB

typedef short s16x8 __attribute__((ext_vector_type(8)));
typedef int   i32x4 __attribute__((ext_vector_type(4)));
typedef float f32x4 __attribute__((ext_vector_type(4)));

__device__ __forceinline__ unsigned short f2bf(float f) {
    unsigned u = __float_as_uint(f);
    unsigned r = u + 0x7FFFu + ((u >> 16) & 1u);   // RTNE
    return (unsigned short)(r >> 16);
}
__device__ __forceinline__ float bf2f(unsigned short h) {
    return __uint_as_float(((unsigned)h) << 16);
}
__device__ __forceinline__ void load_lds16(const void* g, void* l) {
    __builtin_amdgcn_global_load_lds((const __attribute__((address_space(1))) void*)g,
                                     (__attribute__((address_space(3))) void*)l,
                                     16, 0, 0);
}
__device__ __forceinline__ signed char q8(float v, float s) {
    return (signed char)__float2int_rn(fminf(fmaxf(v * s, -127.0f), 127.0f));
}

// ---------- fused prep: quant_x + split(cb) + split(W) + norms zero ----------
__global__ __launch_bounds__(256) void prep(
        const float* __restrict__ x, const float* __restrict__ cb, const float* __restrict__ W,
        signed char* __restrict__ xq,
        unsigned short* __restrict__ cbh, unsigned short* __restrict__ cbl,
        unsigned short* __restrict__ wh, unsigned short* __restrict__ wl,
        float* __restrict__ norms) {
    const int b = blockIdx.x;
    const int t = threadIdx.x;
    if (b < 8192) {
        const int i = b * 256 + t;
        float4 v = ((const float4*)x)[i];
        char4 c;
        c.x = q8(v.x, SX); c.y = q8(v.y, SX); c.z = q8(v.z, SX); c.w = q8(v.w, SX);
        ((char4*)xq)[i] = c;
    } else if (b < 12288) {
        const int i = (b - 8192) * 256 + t;
        float4 v = ((const float4*)cb)[i];
        ushort4 h, l;
        h.x = f2bf(v.x); l.x = f2bf(v.x - bf2f(h.x));
        h.y = f2bf(v.y); l.y = f2bf(v.y - bf2f(h.y));
        h.z = f2bf(v.z); l.z = f2bf(v.z - bf2f(h.z));
        h.w = f2bf(v.w); l.w = f2bf(v.w - bf2f(h.w));
        ((ushort4*)cbh)[i] = h;
        ((ushort4*)cbl)[i] = l;
    } else if (b < 12544) {
        const int i = (b - 12288) * 256 + t;
        float4 v = ((const float4*)W)[i];
        ushort4 h, l;
        h.x = f2bf(v.x); l.x = f2bf(v.x - bf2f(h.x));
        h.y = f2bf(v.y); l.y = f2bf(v.y - bf2f(h.y));
        h.z = f2bf(v.z); l.z = f2bf(v.z - bf2f(h.z));
        h.w = f2bf(v.w); l.w = f2bf(v.w - bf2f(h.w));
        ((ushort4*)wh)[i] = h;
        ((ushort4*)wl)[i] = l;
    } else {
        const int i = (b - 12544) * 256 + t;   // 0..8191
        norms[i] = 0.0f;
    }
}

// ------ codes = cb @ W^T via bf16 hi/lo 3-pass MFMA; emit f32 + i8 + norms ------
// grid (CBN/128, 512/128) = (64,4), 512 threads = 8 waves (wm 0..3 x wn 0..1),
// wave tile 32x64, acc[2][4]. Swizzled LDS, 2-phase double-buffered pipeline.
__global__ __launch_bounds__(512) void codes_mfma(
        const unsigned short* __restrict__ Ah_g, const unsigned short* __restrict__ Al_g,
        const unsigned short* __restrict__ Bh_g, const unsigned short* __restrict__ Bl_g,
        float* __restrict__ C, signed char* __restrict__ Cq, float* __restrict__ Norms) {
    __shared__ __align__(16) unsigned short Ahi[2][128 * 32];
    __shared__ __align__(16) unsigned short Alo[2][128 * 32];
    __shared__ __align__(16) unsigned short Bhi[2][128 * 32];
    __shared__ __align__(16) unsigned short Blo[2][128 * 32];

    const int t    = threadIdx.x;
    const int w    = t >> 6;
    const int lane = t & 63;
    const int quad = lane >> 4;
    const int l16  = lane & 15;
    const int wm   = w & 3, wn = w >> 2;
    const int rowBase = blockIdx.x * 128;
    const int colBase = blockIdx.y * 128;

    f32x4 acc[2][4];
    #pragma unroll
    for (int i = 0; i < 2; ++i)
        #pragma unroll
        for (int j = 0; j < 4; ++j)
            acc[i][j] = (f32x4)(0.0f);

    const int mr = t >> 2;                             // 0..127
    const int kq = ((t & 3) ^ ((t >> 3) & 3)) * 8;     // swizzled source chunk (ushorts)
    const size_t gxa = (size_t)(rowBase + mr) * DIMK + kq;
    const size_t gca = (size_t)(colBase + mr) * DIMK + kq;
    const int l0 = w * 512;                            // wave-uniform LDS ushort base

    const int swz8 = (quad ^ ((l16 >> 1) & 3)) * 8;    // swizzled read chunk (ushorts)

#define CODES_STAGE(NXT, K0)                                   \
    do {                                                       \
        load_lds16(Ah_g + gxa + (K0), &Ahi[NXT][l0]);          \
        load_lds16(Al_g + gxa + (K0), &Alo[NXT][l0]);          \
        load_lds16(Bh_g + gca + (K0), &Bhi[NXT][l0]);          \
        load_lds16(Bl_g + gca + (K0), &Blo[NXT][l0]);          \
    } while (0)

#define CODES_COMPUTE(CUR)                                                                         \
    do {                                                                                           \
        s16x8 ah[2], al[2], bh[4], bl[4];                                                          \
        _Pragma("unroll")                                                                          \
        for (int i = 0; i < 2; ++i) {                                                              \
            const int m = wm * 32 + i * 16 + l16;                                                  \
            ah[i] = *(const s16x8*)&Ahi[CUR][m * 32 + swz8];                                       \
            al[i] = *(const s16x8*)&Alo[CUR][m * 32 + swz8];                                       \
        }                                                                                          \
        _Pragma("unroll")                                                                          \
        for (int j = 0; j < 4; ++j) {                                                              \
            const int n = wn * 64 + j * 16 + l16;                                                  \
            bh[j] = *(const s16x8*)&Bhi[CUR][n * 32 + swz8];                                       \
            bl[j] = *(const s16x8*)&Blo[CUR][n * 32 + swz8];                                       \
        }                                                                                          \
        _Pragma("unroll")                                                                          \
        for (int i = 0; i < 2; ++i)                                                                \
            _Pragma("unroll")                                                                      \
            for (int j = 0; j < 4; ++j) {                                                          \
                acc[i][j] = __builtin_amdgcn_mfma_f32_16x16x32_bf16(ah[i], bh[j], acc[i][j], 0, 0, 0); \
                acc[i][j] = __builtin_amdgcn_mfma_f32_16x16x32_bf16(ah[i], bl[j], acc[i][j], 0, 0, 0); \
                acc[i][j] = __builtin_amdgcn_mfma_f32_16x16x32_bf16(al[i], bh[j], acc[i][j], 0, 0, 0); \
            }                                                                                      \
    } while (0)

    // prologue: stage k0=0 into buf0
    CODES_STAGE(0, 0);
    asm volatile("s_waitcnt vmcnt(0)" ::: "memory");
    __syncthreads();

    for (int k0 = 0; k0 < DIMK; k0 += 64) {
        CODES_STAGE(1, k0 + 32);
        CODES_COMPUTE(0);
        asm volatile("s_waitcnt vmcnt(0)" ::: "memory");
        __syncthreads();
        if (k0 + 64 < DIMK) {
            CODES_STAGE(0, k0 + 64);
            CODES_COMPUTE(1);
            asm volatile("s_waitcnt vmcnt(0)" ::: "memory");
            __syncthreads();
        } else {
            CODES_COMPUTE(1);
        }
    }
#undef CODES_STAGE
#undef CODES_COMPUTE

    // epilogue: C/D layout col = j*16+l16, row = i*16+quad*4+r
    #pragma unroll
    for (int i = 0; i < 2; ++i) {
        #pragma unroll
        for (int r = 0; r < 4; ++r) {
            const int row = rowBase + wm * 32 + i * 16 + quad * 4 + r;
            float nsum = 0.0f;
            #pragma unroll
            for (int j = 0; j < 4; ++j) {
                const int col = colBase + wn * 64 + j * 16 + l16;
                const float v = acc[i][j][r];
                C[(size_t)row * DIMK + col] = v;
                Cq[(size_t)row * DIMK + col] = q8(v, SC);
                nsum = fmaf(v, v, nsum);
            }
            nsum += __shfl_xor(nsum, 1, 64);
            nsum += __shfl_xor(nsum, 2, 64);
            nsum += __shfl_xor(nsum, 4, 64);
            nsum += __shfl_xor(nsum, 8, 64);
            if (l16 == 0) atomicAdd(&Norms[row], nsum);
        }
    }
}

// ---------- i8 distance GEMM (MFMA 16x16x64) + branch-free top-3 emission ----------
// grid: (MROWS/128, CBN/128), 512 threads = 8 waves (4x2), wave tile 32x64 (acc 2x4).
// Swizzled LDS (conflict-free), 2-phase double-buffered pipeline.  [UNCHANGED R9]
__global__ __launch_bounds__(512, 6) void d2_argmin_i8(
        const signed char* __restrict__ Xq,
        const signed char* __restrict__ Cq,
        const float* __restrict__ Norms,
        unsigned* __restrict__ Cand) {
    __shared__ __align__(16) signed char Ash[2][128 * 64];
    __shared__ __align__(16) signed char Bsh[2][128 * 64];

    const int t    = threadIdx.x;
    const int w    = t >> 6;
    const int lane = t & 63;
    const int quad = lane >> 4;
    const int l16  = lane & 15;
    const int wm   = w & 3, wn = w >> 2;
    const int rowBase = blockIdx.x * 128;
    const int colBase = blockIdx.y * 128;

    i32x4 acc[2][4];
    #pragma unroll
    for (int i = 0; i < 2; ++i)
        #pragma unroll
        for (int j = 0; j < 4; ++j)
            acc[i][j] = (i32x4)(0);

    const int mr  = t >> 2;                              // 0..127
    const int kcs = ((t & 3) ^ ((t >> 3) & 3)) * 16;     // swizzled source chunk (bytes)
    const size_t gxa = (size_t)(rowBase + mr) * DIMK + kcs;
    const size_t gca = (size_t)(colBase + mr) * DIMK + kcs;
    const int lb = w * 1024;            // wave-uniform LDS byte base

    const int swz  = (quad ^ ((l16 >> 1) & 3)) * 16;
    const int aoff = (wm * 32 + l16) * 64 + swz;
    const int boff = (wn * 64 + l16) * 64 + swz;

    // key bias per column group: nq = norm*4096 + 65536
    float nq[4];
    #pragma unroll
    for (int j = 0; j < 4; ++j)
        nq[j] = fmaf(Norms[colBase + wn * 64 + j * 16 + l16], 4096.0f, 65536.0f);

#define D2_STEP(CUR, NXT, K0, DO_STAGE, DO_SYNC)                                                   \
    do {                                                                                           \
        if (DO_STAGE) {                                                                            \
            load_lds16(Xq + gxa + (K0) + 64, &Ash[NXT][lb]);                                       \
            load_lds16(Cq + gca + (K0) + 64, &Bsh[NXT][lb]);                                       \
        }                                                                                          \
        i32x4 af0 = *(const i32x4*)&Ash[CUR][aoff];                                                \
        i32x4 af1 = *(const i32x4*)&Ash[CUR][aoff + 1024];                                         \
        _Pragma("unroll")                                                                          \
        for (int j = 0; j < 4; ++j) {                                                              \
            const i32x4 bfj = *(const i32x4*)&Bsh[CUR][boff + j * 1024];                           \
            acc[0][j] = __builtin_amdgcn_mfma_i32_16x16x64_i8(af0, bfj, acc[0][j], 0, 0, 0);       \
            acc[1][j] = __builtin_amdgcn_mfma_i32_16x16x64_i8(af1, bfj, acc[1][j], 0, 0, 0);       \
        }                                                                                          \
        if (DO_SYNC) {                                                                             \
            asm volatile("s_waitcnt vmcnt(0)" ::: "memory");                                       \
            __syncthreads();                                                                       \
        }                                                                                          \
    } while (0)

    // prologue: stage k0=0 into buf0
    load_lds16(Xq + gxa, &Ash[0][lb]);
    load_lds16(Cq + gca, &Bsh[0][lb]);
    asm volatile("s_waitcnt vmcnt(0)" ::: "memory");
    __syncthreads();

    D2_STEP(0, 1,   0, true,  true);
    D2_STEP(1, 0,  64, true,  true);
    D2_STEP(0, 1, 128, true,  true);
    D2_STEP(1, 0, 192, true,  true);
    D2_STEP(0, 1, 256, true,  true);
    D2_STEP(1, 0, 320, true,  true);
    D2_STEP(0, 1, 384, true,  true);   // stages 448 into buf1
    D2_STEP(1, 0, 448, false, false);  // final, no stage, no trailing sync
#undef D2_STEP

    // ---- branch-free top-3 per (row, 64-col subtile) ----
    const unsigned colG = colBase + wn * 64 + l16;
    const int subtile = blockIdx.y * 2 + wn;
    const float C2 = -8192.0f * INV_SS;

    #pragma unroll
    for (int i = 0; i < 2; ++i) {
        #pragma unroll
        for (int r = 0; r < 4; ++r) {
            unsigned k[4];
            #pragma unroll
            for (int j = 0; j < 4; ++j) {
                const float kf = fmaf((float)acc[i][j][r], C2, nq[j]);
                int ki = (int)kf;
                ki = ki < 0 ? 0 : ki;
                ki = ki > 524287 ? 524287 : ki;
                k[j] = ((unsigned)ki << 13) | (colG + j * 16);
            }
            unsigned lo01 = min(k[0], k[1]), hi01 = max(k[0], k[1]);
            unsigned lo23 = min(k[2], k[3]), hi23 = max(k[2], k[3]);
            unsigned a0 = min(lo01, lo23);
            unsigned m  = max(lo01, lo23);
            unsigned tt = min(hi01, hi23);
            unsigned a1 = min(m, tt);
            unsigned a2 = max(m, tt);
            #pragma unroll
            for (int mk = 1; mk < 16; mk <<= 1) {
                const unsigned b0 = __shfl_xor(a0, mk, 64);
                const unsigned b1 = __shfl_xor(a1, mk, 64);
                const unsigned b2 = __shfl_xor(a2, mk, 64);
                const unsigned M0 = max(a0, b0);
                const unsigned m1 = min(a1, b1);
                const unsigned n0 = min(a0, b0);
                a2 = min(max(m1, M0), min(a2, b2));
                a1 = min(M0, m1);
                a0 = n0;
            }
            if (l16 == 0) {
                const int row = rowBase + wm * 32 + i * 16 + quad * 4 + r;
                unsigned* slot = Cand + ((size_t)row * 128 + subtile) * NSLOT;
                slot[0] = a0; slot[1] = a1; slot[2] = a2;
            }
        }
    }
}

// ---------- refine candidates exactly (f32) + gather + loss partial ----------
// Quad-parallel: 4 candidates in flight (one per 16-lane quad), each lane covers
// 32 elems of the dot; 4-level quad reduce. Final exact (d2, idx) lexicographic
// wave reduce preserves argmin lowest-index tie semantics.
__global__ __launch_bounds__(256) void refine_gather(
        const float* __restrict__ X, const float* __restrict__ Codes,
        const float* __restrict__ Norms, const unsigned* __restrict__ Cand,
        float* __restrict__ outQ, float* __restrict__ outIdx,
        float* __restrict__ lossP) {
    const int t    = threadIdx.x;
    const int w    = t >> 6;
    const int lane = t & 63;
    const int quad = lane >> 4;
    const int l16  = lane & 15;
    const int row  = blockIdx.x * 4 + w;

    const unsigned* cp = Cand + (size_t)row * 128 * NSLOT + lane * 6;
    unsigned sl[6];
    #pragma unroll
    for (int s = 0; s < 6; ++s) sl[s] = cp[s];

    unsigned mn = sl[0];
    #pragma unroll
    for (int s = 1; s < 6; ++s) mn = min(mn, sl[s]);
    #pragma unroll
    for (int mask = 1; mask < 64; mask <<= 1)
        mn = min(mn, (unsigned)__shfl((int)mn, lane ^ mask, 64));
    const unsigned thrp = (((mn >> 13) + DKEY) << 13) | 0x1FFFu;

    // x slice for quad-dot: lane covers elems [l16*32, l16*32+32)
    float4 xr[8];
    #pragma unroll
    for (int u = 0; u < 8; ++u)
        xr[u] = *(const float4*)(X + (size_t)row * DIMK + l16 * 32 + u * 4);

    float bestD = __builtin_inff();
    unsigned bestIdx = 0xFFFFFFFFu;

    #pragma unroll
    for (int s = 0; s < 6; ++s) {
        unsigned long long bm = __ballot(sl[s] <= thrp);
        while (bm) {
            // quad q evaluates the q-th lowest set bit (if present)
            unsigned long long mq = bm;
            if (quad >= 1) mq &= mq - 1;
            if (quad >= 2) mq &= mq - 1;
            if (quad >= 3) mq &= mq - 1;
            const bool act = (mq != 0ull);
            const int src = act ? (__ffsll((long long)mq) - 1) : 0;
            const unsigned sv = (unsigned)__shfl((int)sl[s], src, 64);
            const unsigned idx = sv & 0x1FFFu;
            const float* cr = Codes + (size_t)idx * DIMK + l16 * 32;
            float s2 = 0.0f;
            #pragma unroll
            for (int u = 0; u < 8; ++u) {
                const float4 cv = *(const float4*)(cr + u * 4);
                s2 += xr[u].x * cv.x + xr[u].y * cv.y + xr[u].z * cv.z + xr[u].w * cv.w;
            }
            s2 += __shfl_xor(s2, 1, 64);
            s2 += __shfl_xor(s2, 2, 64);
            s2 += __shfl_xor(s2, 4, 64);
            s2 += __shfl_xor(s2, 8, 64);
            const float d2 = fmaf(-2.0f, s2, Norms[idx]);
            if (act && (d2 < bestD || (d2 == bestD && idx < bestIdx))) {
                bestD = d2; bestIdx = idx;
            }
            bm &= bm - 1; bm &= bm - 1; bm &= bm - 1; bm &= bm - 1;   // pop up to 4
        }
    }

    // exact lexicographic (d2, idx) min across all 64 lanes
    #pragma unroll
    for (int mk = 1; mk < 64; mk <<= 1) {
        const float od = __shfl_xor(bestD, mk, 64);
        const unsigned oi = (unsigned)__shfl_xor((int)bestIdx, mk, 64);
        if (od < bestD || (od == bestD && oi < bestIdx)) { bestD = od; bestIdx = oi; }
    }

    // gather + loss (original per-lane-8 layout)
    const float4 xa = *(const float4*)(X + (size_t)row * DIMK + lane * 8);
    const float4 xb = *(const float4*)(X + (size_t)row * DIMK + lane * 8 + 4);
    const float4 qa = *(const float4*)(Codes + (size_t)bestIdx * DIMK + lane * 8);
    const float4 qb = *(const float4*)(Codes + (size_t)bestIdx * DIMK + lane * 8 + 4);
    *(float4*)(outQ + (size_t)row * DIMK + lane * 8) = qa;
    *(float4*)(outQ + (size_t)row * DIMK + lane * 8 + 4) = qb;
    float dx0 = xa.x - qa.x, dx1 = xa.y - qa.y, dx2 = xa.z - qa.z, dx3 = xa.w - qa.w;
    float dy0 = xb.x - qb.x, dy1 = xb.y - qb.y, dy2 = xb.z - qb.z, dy3 = xb.w - qb.w;
    float s = dx0 * dx0 + dx1 * dx1 + dx2 * dx2 + dx3 * dx3
            + dy0 * dy0 + dy1 * dy1 + dy2 * dy2 + dy3 * dy3;
    #pragma unroll
    for (int off = 32; off > 0; off >>= 1) s += __shfl_down(s, off);
    if (lane == 0) {
        lossP[row] = s;
        outIdx[row] = (float)bestIdx;
    }
}

__global__ __launch_bounds__(256) void finalize_loss(const float* __restrict__ lossPartials,
                                                     float* __restrict__ outLoss) {
    const int t = threadIdx.x;
    float s = 0.0f;
    for (int i = t; i < MROWS; i += 256) s += lossPartials[i];
    #pragma unroll
    for (int off = 32; off > 0; off >>= 1) s += __shfl_down(s, off);
    __shared__ float red[4];
    if ((t & 63) == 0) red[t >> 6] = s;
    __syncthreads();
    if (t == 0)
        *outLoss = (red[0] + red[1] + red[2] + red[3]) * (1.0f / (float)((size_t)MROWS * DIMK));
}

extern "C" void kernel_launch(void* const* d_in, const int* in_sizes, int n_in,
                              void* d_out, int out_size, void* d_ws, size_t ws_size,
                              hipStream_t stream) {
    const float* x  = (const float*)d_in[0];
    const float* cb = (const float*)d_in[1];
    const float* W  = (const float*)d_in[2];
    float* out = (float*)d_out;

    char* ws = (char*)d_ws;
    float* codes          = (float*)(ws + WS_CODES);
    signed char* xq       = (signed char*)(ws + WS_XQ);
    signed char* cq       = (signed char*)(ws + WS_CQ);
    float* norms          = (float*)(ws + WS_NORMS);
    unsigned* cand        = (unsigned*)(ws + WS_CAND);
    unsigned short* cbh   = (unsigned short*)(ws + WS_CBH);   // aliases cand
    unsigned short* cbl   = (unsigned short*)(ws + WS_CBL);   // aliases cand
    unsigned short* wh    = (unsigned short*)(ws + WS_WH);
    unsigned short* wl    = (unsigned short*)(ws + WS_WL);
    float* lossP          = (float*)(ws + WS_LOSSP);

    // fused prep: x->i8, cb/W->bf16 hi/lo, norms zero
    prep<<<12576, 256, 0, stream>>>(x, cb, W, xq, cbh, cbl, wh, wl, norms);

    // codes = cb @ W^T (3-pass hi/lo MFMA, 512 thr / 8 waves, 2-phase pipeline)
    codes_mfma<<<dim3(CBN / 128, DIMK / 128), 512, 0, stream>>>(cbh, cbl, wh, wl, codes, cq, norms);

    // i8 MFMA distance + branch-free top-3 emission (unchanged)
    d2_argmin_i8<<<dim3(MROWS / 128, CBN / 128), 512, 0, stream>>>(xq, cq, norms, cand);

    // exact refine (quad-parallel dots) + gather + loss partials
    refine_gather<<<MROWS / 4, 256, 0, stream>>>(x, codes, norms, cand, out,
                                                 out + (size_t)MROWS * DIMK, lossP);
    finalize_loss<<<1, 256, 0, stream>>>(lossP, out + (size_t)MROWS * DIMK + MROWS);
}

// Round 6
// 265.381 us; speedup vs baseline: 1.1680x; 1.1680x over previous
//
#include <hip/hip_runtime.h>

// SimVQ: x[8,2048,512] f32, codebook[8192,512] f32, W[512,512] f32
// out = concat(quantized[16384*512], indices[16384] (as f32), commit_loss[1])
//
// Round 12 == Round 11 resubmit (R11 bench was an infra failure, no data):
//  R10 post-mortem: +17us regression. Quad-parallel refine ADDED gather traffic
//  (inactive quads fetch 2KB rows; typically only 1-4 candidates pass the band)
//  -> reverted to R9 serial refine. codes_mfma 512-thr kept (2 waves/SIMD on a
//  1-block/CU kernel; mechanism sound, attribution now clean).
//  finalize_loss was a 64-deep serial scalar load chain on ONE CU (latency-bound,
//  est 5-20us) -> 1024 thr x 4 parallel float4 loads (~2us).
//  d2_argmin_i8 frozen (145us, MfmaUtil 21 / VALU 54 / occ 65).

#define DIMK  512
#define CBN   8192
#define MROWS 16384

#define SX 24.0f
#define SC 500.0f
#define INV_SS (1.0f / (SX * SC))
#define DKEY  1231
#define NSLOT 3

// ws layout (bytes)
#define WS_CODES   0UL          // 8192*512*4    = 16,777,216
#define WS_XQ      16777216UL   // 16384*512     =  8,388,608
#define WS_CQ      25165824UL   // 8192*512      =  4,194,304
#define WS_NORMS   29360128UL   // 8192*4
#define WS_CAND    29392896UL   // 16384*128*3*4 = 25,165,824
#define WS_CBH     29392896UL   // alias: cb hi (consumed before d2 writes cand)
#define WS_CBL     37781504UL   // alias: cb lo
#define WS_WH      54558720UL   // 512*512*2 = 524,288
#define WS_WL      55083008UL
#define WS_LOSSP   55607296UL   // 16384*4
// end ~55.7 MB

typedef short s16x8 __attribute__((ext_vector_type(8)));
typedef int   i32x4 __attribute__((ext_vector_type(4)));
typedef float f32x4 __attribute__((ext_vector_type(4)));

__device__ __forceinline__ unsigned short f2bf(float f) {
    unsigned u = __float_as_uint(f);
    unsigned r = u + 0x7FFFu + ((u >> 16) & 1u);   // RTNE
    return (unsigned short)(r >> 16);
}
__device__ __forceinline__ float bf2f(unsigned short h) {
    return __uint_as_float(((unsigned)h) << 16);
}
__device__ __forceinline__ void load_lds16(const void* g, void* l) {
    __builtin_amdgcn_global_load_lds((const __attribute__((address_space(1))) void*)g,
                                     (__attribute__((address_space(3))) void*)l,
                                     16, 0, 0);
}
__device__ __forceinline__ signed char q8(float v, float s) {
    return (signed char)__float2int_rn(fminf(fmaxf(v * s, -127.0f), 127.0f));
}

// ---------- fused prep: quant_x + split(cb) + split(W) + norms zero ----------
__global__ __launch_bounds__(256) void prep(
        const float* __restrict__ x, const float* __restrict__ cb, const float* __restrict__ W,
        signed char* __restrict__ xq,
        unsigned short* __restrict__ cbh, unsigned short* __restrict__ cbl,
        unsigned short* __restrict__ wh, unsigned short* __restrict__ wl,
        float* __restrict__ norms) {
    const int b = blockIdx.x;
    const int t = threadIdx.x;
    if (b < 8192) {
        const int i = b * 256 + t;
        float4 v = ((const float4*)x)[i];
        char4 c;
        c.x = q8(v.x, SX); c.y = q8(v.y, SX); c.z = q8(v.z, SX); c.w = q8(v.w, SX);
        ((char4*)xq)[i] = c;
    } else if (b < 12288) {
        const int i = (b - 8192) * 256 + t;
        float4 v = ((const float4*)cb)[i];
        ushort4 h, l;
        h.x = f2bf(v.x); l.x = f2bf(v.x - bf2f(h.x));
        h.y = f2bf(v.y); l.y = f2bf(v.y - bf2f(h.y));
        h.z = f2bf(v.z); l.z = f2bf(v.z - bf2f(h.z));
        h.w = f2bf(v.w); l.w = f2bf(v.w - bf2f(h.w));
        ((ushort4*)cbh)[i] = h;
        ((ushort4*)cbl)[i] = l;
    } else if (b < 12544) {
        const int i = (b - 12288) * 256 + t;
        float4 v = ((const float4*)W)[i];
        ushort4 h, l;
        h.x = f2bf(v.x); l.x = f2bf(v.x - bf2f(h.x));
        h.y = f2bf(v.y); l.y = f2bf(v.y - bf2f(h.y));
        h.z = f2bf(v.z); l.z = f2bf(v.z - bf2f(h.z));
        h.w = f2bf(v.w); l.w = f2bf(v.w - bf2f(h.w));
        ((ushort4*)wh)[i] = h;
        ((ushort4*)wl)[i] = l;
    } else {
        const int i = (b - 12544) * 256 + t;   // 0..8191
        norms[i] = 0.0f;
    }
}

// ------ codes = cb @ W^T via bf16 hi/lo 3-pass MFMA; emit f32 + i8 + norms ------
// grid (CBN/128, 512/128) = (64,4), 512 threads = 8 waves (wm 0..3 x wn 0..1),
// wave tile 32x64, acc[2][4]. Swizzled LDS, 2-phase double-buffered pipeline.
__global__ __launch_bounds__(512) void codes_mfma(
        const unsigned short* __restrict__ Ah_g, const unsigned short* __restrict__ Al_g,
        const unsigned short* __restrict__ Bh_g, const unsigned short* __restrict__ Bl_g,
        float* __restrict__ C, signed char* __restrict__ Cq, float* __restrict__ Norms) {
    __shared__ __align__(16) unsigned short Ahi[2][128 * 32];
    __shared__ __align__(16) unsigned short Alo[2][128 * 32];
    __shared__ __align__(16) unsigned short Bhi[2][128 * 32];
    __shared__ __align__(16) unsigned short Blo[2][128 * 32];

    const int t    = threadIdx.x;
    const int w    = t >> 6;
    const int lane = t & 63;
    const int quad = lane >> 4;
    const int l16  = lane & 15;
    const int wm   = w & 3, wn = w >> 2;
    const int rowBase = blockIdx.x * 128;
    const int colBase = blockIdx.y * 128;

    f32x4 acc[2][4];
    #pragma unroll
    for (int i = 0; i < 2; ++i)
        #pragma unroll
        for (int j = 0; j < 4; ++j)
            acc[i][j] = (f32x4)(0.0f);

    const int mr = t >> 2;                             // 0..127
    const int kq = ((t & 3) ^ ((t >> 3) & 3)) * 8;     // swizzled source chunk (ushorts)
    const size_t gxa = (size_t)(rowBase + mr) * DIMK + kq;
    const size_t gca = (size_t)(colBase + mr) * DIMK + kq;
    const int l0 = w * 512;                            // wave-uniform LDS ushort base

    const int swz8 = (quad ^ ((l16 >> 1) & 3)) * 8;    // swizzled read chunk (ushorts)

#define CODES_STAGE(NXT, K0)                                   \
    do {                                                       \
        load_lds16(Ah_g + gxa + (K0), &Ahi[NXT][l0]);          \
        load_lds16(Al_g + gxa + (K0), &Alo[NXT][l0]);          \
        load_lds16(Bh_g + gca + (K0), &Bhi[NXT][l0]);          \
        load_lds16(Bl_g + gca + (K0), &Blo[NXT][l0]);          \
    } while (0)

#define CODES_COMPUTE(CUR)                                                                         \
    do {                                                                                           \
        s16x8 ah[2], al[2], bh[4], bl[4];                                                          \
        _Pragma("unroll")                                                                          \
        for (int i = 0; i < 2; ++i) {                                                              \
            const int m = wm * 32 + i * 16 + l16;                                                  \
            ah[i] = *(const s16x8*)&Ahi[CUR][m * 32 + swz8];                                       \
            al[i] = *(const s16x8*)&Alo[CUR][m * 32 + swz8];                                       \
        }                                                                                          \
        _Pragma("unroll")                                                                          \
        for (int j = 0; j < 4; ++j) {                                                              \
            const int n = wn * 64 + j * 16 + l16;                                                  \
            bh[j] = *(const s16x8*)&Bhi[CUR][n * 32 + swz8];                                       \
            bl[j] = *(const s16x8*)&Blo[CUR][n * 32 + swz8];                                       \
        }                                                                                          \
        _Pragma("unroll")                                                                          \
        for (int i = 0; i < 2; ++i)                                                                \
            _Pragma("unroll")                                                                      \
            for (int j = 0; j < 4; ++j) {                                                          \
                acc[i][j] = __builtin_amdgcn_mfma_f32_16x16x32_bf16(ah[i], bh[j], acc[i][j], 0, 0, 0); \
                acc[i][j] = __builtin_amdgcn_mfma_f32_16x16x32_bf16(ah[i], bl[j], acc[i][j], 0, 0, 0); \
                acc[i][j] = __builtin_amdgcn_mfma_f32_16x16x32_bf16(al[i], bh[j], acc[i][j], 0, 0, 0); \
            }                                                                                      \
    } while (0)

    // prologue: stage k0=0 into buf0
    CODES_STAGE(0, 0);
    asm volatile("s_waitcnt vmcnt(0)" ::: "memory");
    __syncthreads();

    for (int k0 = 0; k0 < DIMK; k0 += 64) {
        CODES_STAGE(1, k0 + 32);
        CODES_COMPUTE(0);
        asm volatile("s_waitcnt vmcnt(0)" ::: "memory");
        __syncthreads();
        if (k0 + 64 < DIMK) {
            CODES_STAGE(0, k0 + 64);
            CODES_COMPUTE(1);
            asm volatile("s_waitcnt vmcnt(0)" ::: "memory");
            __syncthreads();
        } else {
            CODES_COMPUTE(1);
        }
    }
#undef CODES_STAGE
#undef CODES_COMPUTE

    // epilogue: C/D layout col = j*16+l16, row = i*16+quad*4+r
    #pragma unroll
    for (int i = 0; i < 2; ++i) {
        #pragma unroll
        for (int r = 0; r < 4; ++r) {
            const int row = rowBase + wm * 32 + i * 16 + quad * 4 + r;
            float nsum = 0.0f;
            #pragma unroll
            for (int j = 0; j < 4; ++j) {
                const int col = colBase + wn * 64 + j * 16 + l16;
                const float v = acc[i][j][r];
                C[(size_t)row * DIMK + col] = v;
                Cq[(size_t)row * DIMK + col] = q8(v, SC);
                nsum = fmaf(v, v, nsum);
            }
            nsum += __shfl_xor(nsum, 1, 64);
            nsum += __shfl_xor(nsum, 2, 64);
            nsum += __shfl_xor(nsum, 4, 64);
            nsum += __shfl_xor(nsum, 8, 64);
            if (l16 == 0) atomicAdd(&Norms[row], nsum);
        }
    }
}

// ---------- i8 distance GEMM (MFMA 16x16x64) + branch-free top-3 emission ----------
// grid: (MROWS/128, CBN/128), 512 threads = 8 waves (4x2), wave tile 32x64 (acc 2x4).
// Swizzled LDS (conflict-free), 2-phase double-buffered pipeline.  [FROZEN since R9]
__global__ __launch_bounds__(512, 6) void d2_argmin_i8(
        const signed char* __restrict__ Xq,
        const signed char* __restrict__ Cq,
        const float* __restrict__ Norms,
        unsigned* __restrict__ Cand) {
    __shared__ __align__(16) signed char Ash[2][128 * 64];
    __shared__ __align__(16) signed char Bsh[2][128 * 64];

    const int t    = threadIdx.x;
    const int w    = t >> 6;
    const int lane = t & 63;
    const int quad = lane >> 4;
    const int l16  = lane & 15;
    const int wm   = w & 3, wn = w >> 2;
    const int rowBase = blockIdx.x * 128;
    const int colBase = blockIdx.y * 128;

    i32x4 acc[2][4];
    #pragma unroll
    for (int i = 0; i < 2; ++i)
        #pragma unroll
        for (int j = 0; j < 4; ++j)
            acc[i][j] = (i32x4)(0);

    const int mr  = t >> 2;                              // 0..127
    const int kcs = ((t & 3) ^ ((t >> 3) & 3)) * 16;     // swizzled source chunk (bytes)
    const size_t gxa = (size_t)(rowBase + mr) * DIMK + kcs;
    const size_t gca = (size_t)(colBase + mr) * DIMK + kcs;
    const int lb = w * 1024;            // wave-uniform LDS byte base

    const int swz  = (quad ^ ((l16 >> 1) & 3)) * 16;
    const int aoff = (wm * 32 + l16) * 64 + swz;
    const int boff = (wn * 64 + l16) * 64 + swz;

    // key bias per column group: nq = norm*4096 + 65536
    float nq[4];
    #pragma unroll
    for (int j = 0; j < 4; ++j)
        nq[j] = fmaf(Norms[colBase + wn * 64 + j * 16 + l16], 4096.0f, 65536.0f);

#define D2_STEP(CUR, NXT, K0, DO_STAGE, DO_SYNC)                                                   \
    do {                                                                                           \
        if (DO_STAGE) {                                                                            \
            load_lds16(Xq + gxa + (K0) + 64, &Ash[NXT][lb]);                                       \
            load_lds16(Cq + gca + (K0) + 64, &Bsh[NXT][lb]);                                       \
        }                                                                                          \
        i32x4 af0 = *(const i32x4*)&Ash[CUR][aoff];                                                \
        i32x4 af1 = *(const i32x4*)&Ash[CUR][aoff + 1024];                                         \
        _Pragma("unroll")                                                                          \
        for (int j = 0; j < 4; ++j) {                                                              \
            const i32x4 bfj = *(const i32x4*)&Bsh[CUR][boff + j * 1024];                           \
            acc[0][j] = __builtin_amdgcn_mfma_i32_16x16x64_i8(af0, bfj, acc[0][j], 0, 0, 0);       \
            acc[1][j] = __builtin_amdgcn_mfma_i32_16x16x64_i8(af1, bfj, acc[1][j], 0, 0, 0);       \
        }                                                                                          \
        if (DO_SYNC) {                                                                             \
            asm volatile("s_waitcnt vmcnt(0)" ::: "memory");                                       \
            __syncthreads();                                                                       \
        }                                                                                          \
    } while (0)

    // prologue: stage k0=0 into buf0
    load_lds16(Xq + gxa, &Ash[0][lb]);
    load_lds16(Cq + gca, &Bsh[0][lb]);
    asm volatile("s_waitcnt vmcnt(0)" ::: "memory");
    __syncthreads();

    D2_STEP(0, 1,   0, true,  true);
    D2_STEP(1, 0,  64, true,  true);
    D2_STEP(0, 1, 128, true,  true);
    D2_STEP(1, 0, 192, true,  true);
    D2_STEP(0, 1, 256, true,  true);
    D2_STEP(1, 0, 320, true,  true);
    D2_STEP(0, 1, 384, true,  true);   // stages 448 into buf1
    D2_STEP(1, 0, 448, false, false);  // final, no stage, no trailing sync
#undef D2_STEP

    // ---- branch-free top-3 per (row, 64-col subtile) ----
    const unsigned colG = colBase + wn * 64 + l16;
    const int subtile = blockIdx.y * 2 + wn;
    const float C2 = -8192.0f * INV_SS;

    #pragma unroll
    for (int i = 0; i < 2; ++i) {
        #pragma unroll
        for (int r = 0; r < 4; ++r) {
            unsigned k[4];
            #pragma unroll
            for (int j = 0; j < 4; ++j) {
                const float kf = fmaf((float)acc[i][j][r], C2, nq[j]);
                int ki = (int)kf;
                ki = ki < 0 ? 0 : ki;
                ki = ki > 524287 ? 524287 : ki;
                k[j] = ((unsigned)ki << 13) | (colG + j * 16);
            }
            unsigned lo01 = min(k[0], k[1]), hi01 = max(k[0], k[1]);
            unsigned lo23 = min(k[2], k[3]), hi23 = max(k[2], k[3]);
            unsigned a0 = min(lo01, lo23);
            unsigned m  = max(lo01, lo23);
            unsigned tt = min(hi01, hi23);
            unsigned a1 = min(m, tt);
            unsigned a2 = max(m, tt);
            #pragma unroll
            for (int mk = 1; mk < 16; mk <<= 1) {
                const unsigned b0 = __shfl_xor(a0, mk, 64);
                const unsigned b1 = __shfl_xor(a1, mk, 64);
                const unsigned b2 = __shfl_xor(a2, mk, 64);
                const unsigned M0 = max(a0, b0);
                const unsigned m1 = min(a1, b1);
                const unsigned n0 = min(a0, b0);
                a2 = min(max(m1, M0), min(a2, b2));
                a1 = min(M0, m1);
                a0 = n0;
            }
            if (l16 == 0) {
                const int row = rowBase + wm * 32 + i * 16 + quad * 4 + r;
                unsigned* slot = Cand + ((size_t)row * 128 + subtile) * NSLOT;
                slot[0] = a0; slot[1] = a1; slot[2] = a2;
            }
        }
    }
}

// ---------- refine candidates exactly (f32) + gather + loss partial ----------
// [R9 serial version]
__global__ __launch_bounds__(256) void refine_gather(
        const float* __restrict__ X, const float* __restrict__ Codes,
        const float* __restrict__ Norms, const unsigned* __restrict__ Cand,
        float* __restrict__ outQ, float* __restrict__ outIdx,
        float* __restrict__ lossP) {
    const int t    = threadIdx.x;
    const int w    = t >> 6;
    const int lane = t & 63;
    const int row  = blockIdx.x * 4 + w;

    const unsigned* cp = Cand + (size_t)row * 128 * NSLOT + lane * 6;
    unsigned sl[6];
    #pragma unroll
    for (int s = 0; s < 6; ++s) sl[s] = cp[s];

    unsigned mn = sl[0];
    #pragma unroll
    for (int s = 1; s < 6; ++s) mn = min(mn, sl[s]);
    #pragma unroll
    for (int mask = 1; mask < 64; mask <<= 1)
        mn = min(mn, (unsigned)__shfl((int)mn, lane ^ mask, 64));
    const unsigned thrp = (((mn >> 13) + DKEY) << 13) | 0x1FFFu;

    const float4 xa = *(const float4*)(X + (size_t)row * DIMK + lane * 8);
    const float4 xb = *(const float4*)(X + (size_t)row * DIMK + lane * 8 + 4);

    float bestD = __builtin_inff();
    unsigned bestIdx = 0xFFFFFFFFu;

    #pragma unroll
    for (int s = 0; s < 6; ++s) {
        unsigned long long bm = __ballot(sl[s] <= thrp);
        while (bm) {
            const int src = __ffsll(bm) - 1;
            bm &= bm - 1;
            const unsigned sv = (unsigned)__shfl((int)sl[s], src, 64);
            const unsigned idx = sv & 0x1FFFu;
            const float4 ca = *(const float4*)(Codes + (size_t)idx * DIMK + lane * 8);
            const float4 cbv = *(const float4*)(Codes + (size_t)idx * DIMK + lane * 8 + 4);
            float s2 = xa.x * ca.x + xa.y * ca.y + xa.z * ca.z + xa.w * ca.w
                     + xb.x * cbv.x + xb.y * cbv.y + xb.z * cbv.z + xb.w * cbv.w;
            #pragma unroll
            for (int mm = 1; mm < 64; mm <<= 1) s2 += __shfl_xor(s2, mm, 64);
            const float d2 = fmaf(-2.0f, s2, Norms[idx]);
            if (d2 < bestD || (d2 == bestD && idx < bestIdx)) { bestD = d2; bestIdx = idx; }
        }
    }

    const float4 qa = *(const float4*)(Codes + (size_t)bestIdx * DIMK + lane * 8);
    const float4 qb = *(const float4*)(Codes + (size_t)bestIdx * DIMK + lane * 8 + 4);
    *(float4*)(outQ + (size_t)row * DIMK + lane * 8) = qa;
    *(float4*)(outQ + (size_t)row * DIMK + lane * 8 + 4) = qb;
    float dx0 = xa.x - qa.x, dx1 = xa.y - qa.y, dx2 = xa.z - qa.z, dx3 = xa.w - qa.w;
    float dy0 = xb.x - qb.x, dy1 = xb.y - qb.y, dy2 = xb.z - qb.z, dy3 = xb.w - qb.w;
    float s = dx0 * dx0 + dx1 * dx1 + dx2 * dx2 + dx3 * dx3
            + dy0 * dy0 + dy1 * dy1 + dy2 * dy2 + dy3 * dy3;
    #pragma unroll
    for (int off = 32; off > 0; off >>= 1) s += __shfl_down(s, off);
    if (lane == 0) {
        lossP[row] = s;
        outIdx[row] = (float)bestIdx;
    }
}

// ---------- finalize: 1024 thr, 4 parallel float4 loads/thread (no serial chain) ----------
__global__ __launch_bounds__(1024) void finalize_loss(const float* __restrict__ lossPartials,
                                                      float* __restrict__ outLoss) {
    const int t = threadIdx.x;
    const float4* p = (const float4*)lossPartials;   // 4096 float4s
    const float4 a = p[t];
    const float4 b = p[t + 1024];
    const float4 c = p[t + 2048];
    const float4 d = p[t + 3072];
    float s = (a.x + a.y + a.z + a.w) + (b.x + b.y + b.z + b.w)
            + (c.x + c.y + c.z + c.w) + (d.x + d.y + d.z + d.w);
    #pragma unroll
    for (int off = 32; off > 0; off >>= 1) s += __shfl_down(s, off);
    __shared__ float red[16];
    if ((t & 63) == 0) red[t >> 6] = s;
    __syncthreads();
    if (t < 64) {
        float v = (t < 16) ? red[t] : 0.0f;
        v += __shfl_down(v, 8, 64);
        v += __shfl_down(v, 4, 64);
        v += __shfl_down(v, 2, 64);
        v += __shfl_down(v, 1, 64);
        if (t == 0)
            *outLoss = v * (1.0f / (float)((size_t)MROWS * DIMK));
    }
}

extern "C" void kernel_launch(void* const* d_in, const int* in_sizes, int n_in,
                              void* d_out, int out_size, void* d_ws, size_t ws_size,
                              hipStream_t stream) {
    const float* x  = (const float*)d_in[0];
    const float* cb = (const float*)d_in[1];
    const float* W  = (const float*)d_in[2];
    float* out = (float*)d_out;

    char* ws = (char*)d_ws;
    float* codes          = (float*)(ws + WS_CODES);
    signed char* xq       = (signed char*)(ws + WS_XQ);
    signed char* cq       = (signed char*)(ws + WS_CQ);
    float* norms          = (float*)(ws + WS_NORMS);
    unsigned* cand        = (unsigned*)(ws + WS_CAND);
    unsigned short* cbh   = (unsigned short*)(ws + WS_CBH);   // aliases cand
    unsigned short* cbl   = (unsigned short*)(ws + WS_CBL);   // aliases cand
    unsigned short* wh    = (unsigned short*)(ws + WS_WH);
    unsigned short* wl    = (unsigned short*)(ws + WS_WL);
    float* lossP          = (float*)(ws + WS_LOSSP);

    // fused prep: x->i8, cb/W->bf16 hi/lo, norms zero
    prep<<<12576, 256, 0, stream>>>(x, cb, W, xq, cbh, cbl, wh, wl, norms);

    // codes = cb @ W^T (3-pass hi/lo MFMA, 512 thr / 8 waves, 2-phase pipeline)
    codes_mfma<<<dim3(CBN / 128, DIMK / 128), 512, 0, stream>>>(cbh, cbl, wh, wl, codes, cq, norms);

    // i8 MFMA distance + branch-free top-3 emission (frozen)
    d2_argmin_i8<<<dim3(MROWS / 128, CBN / 128), 512, 0, stream>>>(xq, cq, norms, cand);

    // exact refine (serial, R9) + gather + loss partials
    refine_gather<<<MROWS / 4, 256, 0, stream>>>(x, codes, norms, cand, out,
                                                 out + (size_t)MROWS * DIMK, lossP);
    finalize_loss<<<1, 1024, 0, stream>>>(lossP, out + (size_t)MROWS * DIMK + MROWS);
}